// Round 6
// baseline (256.396 us; speedup 1.0000x reference)
//
#include <hip/hip_runtime.h>
#include <hip/hip_bf16.h>

// LinearAttentionTriton: out_t = Q_t @ (K_t^T @ V_t) @ S,  S = V^T K (fp32)
// N = 262144, D = 64, TRUNK = 128, fp32 in/out.
//
// Round-9 == round-6/7/8 resubmit. Rounds 6-8 all died at container
// ACQUISITION (no timing JSON => kernel never executed); source has been
// audited 3x: all accesses in-bounds and 16B-aligned, no hang vectors, no
// graph-capture violations. Pre-committed fallback: if this also dies
// infra-style, next round bisects with the round-5 known-passed kernel.
//
// g_kernel is a barrier-free direct-gather kernel: three measured rounds
// showed every stage->barrier->MFMA variant pins at ~1.5 TB/s
// (latency-chained, MfmaUtil ~1%, VALUBusy ~5%). The LDS transpose existed
// only to build MFMA fragments = "8 stride-64 floats per lane"; those are
// now gathered straight from global (16-lane/64B-line coalesced scalar
// loads, 4 lines/instr; intra-block 2x wave duplication is L2-absorbed).
// No LDS, no barriers, no atomics in g_kernel: partial S sums go back to
// the proven partials + s_reduce path.
//
// d_out memory map during the pipeline (pair-region g = 64 KB for trunks
// {2g, 2g+1}):
//   [g*64K        , g*64K + 16K)  G pair (bf16)  - written by g_kernel,
//                                                  read by out_kernel blk g
//   [g*64K + 16K  , g*64K + 32K)  S-partial of g_kernel block g (fp32)
//                                                  - read by s_reduce
// out_kernel block g overwrites its whole region last. Disjoint, race-free,
// stream-serialized. ws usage: 16 KB (S only).
// Numerics: identical MFMAs, identical f2bf rounding points, fp32 S
// accumulation with the round-1-verified partial/reduce grouping.

#define TRUNK 128
#define DD 64

typedef __bf16 bf16x8 __attribute__((ext_vector_type(8)));
typedef float  f32x4  __attribute__((ext_vector_type(4)));
typedef unsigned int   u32;
typedef unsigned short u16;
typedef u32 u32x4 __attribute__((ext_vector_type(4)));
typedef u32 u32x2 __attribute__((ext_vector_type(2)));

union F8 { bf16x8 v; u16 u[8]; u32x4 q; };

__device__ __forceinline__ u16 f2bf(float x) {
    union { float f; u32 u; } a; a.f = x;
    u32 u = a.u;
    return (u16)((u + 0x7FFFu + ((u >> 16) & 1u)) >> 16);
}
__device__ __forceinline__ u32 pack2(float a, float b) {
    return (u32)f2bf(a) | ((u32)f2bf(b) << 16);
}

#define P_S  72    // stride for 64x64 mats (ST/HT): 144 B rows

// ---------------- Kernel 1: per-trunk G_t = (K_t^T V_t)^T, S-partials -------
// 1024 blocks x 256 threads, 2 trunks each. No LDS, no barriers: MFMA
// fragments (8 stride-64 floats per lane) gathered directly from global.
// Per trunk: 4 k-steps x {32 scalar loads, cvt, 4 MFMA}. G written bf16;
// block's fp32 C1 sum written as one 16 KB partial.
__global__ __launch_bounds__(256, 4) void g_kernel(const float* __restrict__ K,
                                                   const float* __restrict__ V,
                                                   float* __restrict__ outb) {
    const int t    = threadIdx.x;
    const int lane = t & 63;
    const int wave = t >> 6;
    const int l15  = lane & 15;
    const int quad = lane >> 4;
    const int mt0  = (wave >> 1) << 1;
    const int nt0  = (wave & 1) << 1;

    const int am0 = (mt0 + 0) * 16 + l15;   // V cols -> A frags
    const int am1 = (mt0 + 1) * 16 + l15;
    const int bn0 = (nt0 + 0) * 16 + l15;   // K cols -> B frags
    const int bn1 = (nt0 + 1) * 16 + l15;

    u16* G = (u16*)outb;
    f32x4 sacc[2][2] = {};

    #pragma unroll
    for (int tr = 0; tr < 2; ++tr) {
        const int  tt = blockIdx.x * 2 + tr;
        const long tb = (long)tt * (TRUNK * DD);
        const float* Vb = V + tb + (long)quad * 8 * 64;
        const float* Kb = K + tb + (long)quad * 8 * 64;

        f32x4 gacc[2][2] = {};
        #pragma unroll
        for (int kt = 0; kt < 4; ++kt) {
            const int ro = kt * 32 * 64;          // k-step row offset (floats)
            float a0[8], a1[8], b0[8], b1[8];
            #pragma unroll
            for (int i = 0; i < 8; ++i) {
                a0[i] = Vb[ro + i * 64 + am0];
                a1[i] = Vb[ro + i * 64 + am1];
                b0[i] = Kb[ro + i * 64 + bn0];
                b1[i] = Kb[ro + i * 64 + bn1];
            }
            F8 af[2], bf[2];
            #pragma unroll
            for (int j = 0; j < 4; ++j) {
                af[0].q[j] = pack2(a0[2 * j], a0[2 * j + 1]);
                af[1].q[j] = pack2(a1[2 * j], a1[2 * j + 1]);
                bf[0].q[j] = pack2(b0[2 * j], b0[2 * j + 1]);
                bf[1].q[j] = pack2(b1[2 * j], b1[2 * j + 1]);
            }
            gacc[0][0] = __builtin_amdgcn_mfma_f32_16x16x32_bf16(af[0].v, bf[0].v, gacc[0][0], 0, 0, 0);
            gacc[0][1] = __builtin_amdgcn_mfma_f32_16x16x32_bf16(af[0].v, bf[1].v, gacc[0][1], 0, 0, 0);
            gacc[1][0] = __builtin_amdgcn_mfma_f32_16x16x32_bf16(af[1].v, bf[0].v, gacc[1][0], 0, 0, 0);
            gacc[1][1] = __builtin_amdgcn_mfma_f32_16x16x32_bf16(af[1].v, bf[1].v, gacc[1][1], 0, 0, 0);
        }

        // G_t[a][b] = C1[b][a], bf16, at pair-region slot (round-2 layout).
        u16* Gt = G + ((size_t)(tt >> 1) * 32768 + (size_t)(tt & 1) * 4096);
        #pragma unroll
        for (int mi = 0; mi < 2; ++mi)
            #pragma unroll
            for (int ni = 0; ni < 2; ++ni) {
                const int ga  = (nt0 + ni) * 16 + l15;        // G row a
                const int gb0 = (mt0 + mi) * 16 + quad * 4;   // G col b0..b0+3
                const float* g = (const float*)&gacc[mi][ni];
                u32x2 w; w[0] = pack2(g[0], g[1]); w[1] = pack2(g[2], g[3]);
                *(u32x2*)&Gt[ga * 64 + gb0] = w;
                sacc[mi][ni] += gacc[mi][ni];
            }
    }

    // fp32 S-partial (natural layout) at [block*64K + 16K, +16K) of d_out
    float* o = outb + (size_t)blockIdx.x * 16384 + 4096;
    #pragma unroll
    for (int mi = 0; mi < 2; ++mi)
        #pragma unroll
        for (int ni = 0; ni < 2; ++ni) {
            const int b0 = (mt0 + mi) * 16 + quad * 4;
            const int a  = (nt0 + ni) * 16 + l15;
            const float* g = (const float*)&sacc[mi][ni];
            #pragma unroll
            for (int reg = 0; reg < 4; ++reg)
                o[(b0 + reg) * 64 + a] = g[reg];
        }
}

// ---------------- Kernel A2: reduce 1024 partials -> S (fp32) ----------------
// 65536 threads = 1024 float4-groups x 64 ways; 64 atomics/address. S zeroed.
// Partial p lives at float4 offset p*4096 + 1024 of d_out.
__global__ __launch_bounds__(256) void s_reduce(const float* __restrict__ Pb,
                                                float* __restrict__ S) {
    const int tid = blockIdx.x * 256 + threadIdx.x;  // [0, 65536)
    const int eg  = tid & 1023;                       // float4 group of S
    const int way = tid >> 10;                        // [0, 64)
    const float4* p = (const float4*)Pb;
    float4 acc = {0.f, 0.f, 0.f, 0.f};
    #pragma unroll 4
    for (int i = 0; i < 16; ++i) {
        float4 v = p[(size_t)(way * 16 + i) * 4096 + 1024 + eg];
        acc.x += v.x; acc.y += v.y; acc.z += v.z; acc.w += v.w;
    }
    atomicAdd(&S[eg * 4 + 0], acc.x);
    atomicAdd(&S[eg * 4 + 1], acc.y);
    atomicAdd(&S[eg * 4 + 2], acc.z);
    atomicAdd(&S[eg * 4 + 3], acc.w);
}

// ---------------- Kernel 2: out_t = Q_t @ G_t @ S ---------------------------
// (verbatim from the round-5 verified kernel)
// 1024 blocks x 256 threads, 2 trunks each. Reads Q + G (bf16) + S (fp32,
// L2-resident). LDS = S^T + HT only (18432 B). One G-drain barrier, then
// 2 barriers per trunk.
#define LDS3 (2 * 64 * P_S)     // ST (4608 u16) + HT (4608 u16)

__global__ __launch_bounds__(256, 3) void out_kernel(const float* __restrict__ Q,
                                                     const float* __restrict__ S,
                                                     const u16* __restrict__ G,
                                                     float* __restrict__ out) {
    __shared__ __align__(16) u16 lds[LDS3];
    u16* STb = lds;                 // [64][72]  S^T bf16
    u16* HTb = lds + 64 * P_S;      // [64][72]  H^T bf16 (per trunk, reused)

    const int t    = threadIdx.x;
    const int lane = t & 63;
    const int wave = t >> 6;
    const int l15  = lane & 15;
    const int quad = lane >> 4;
    const int mt0  = (wave >> 1) << 1;
    const int nt0  = (wave & 1) << 1;

    // ---- issue G loads for both trunks (A-frags of stage 2) ----------------
    const u16* Gblk = G + (size_t)blockIdx.x * 32768;   // this block's 16 KB
    F8 gf[2][2][2];   // [trunk][kt][mi]
    #pragma unroll
    for (int tr = 0; tr < 2; ++tr)
        #pragma unroll
        for (int kt = 0; kt < 2; ++kt)
            #pragma unroll
            for (int mi = 0; mi < 2; ++mi)
                gf[tr][kt][mi].q = *(const u32x4*)&Gblk[(size_t)tr * 4096 +
                    ((mt0 + mi) * 16 + l15) * 64 + kt * 32 + quad * 8];

    // ---- stage S^T into LDS (fp32 S -> bf16, transposed) -------------------
    {
        const int sb0 = (t & 7) * 8;        // 0..56
        const int sc0 = (t >> 3) * 2;       // 0..62
        float2 sv[8];
        #pragma unroll
        for (int i = 0; i < 8; ++i)
            sv[i] = *(const float2*)(S + (sb0 + i) * 64 + sc0);
        #pragma unroll
        for (int j = 0; j < 2; ++j) {
            u32x4 w;
            w[0] = pack2(((const float*)&sv[0])[j], ((const float*)&sv[1])[j]);
            w[1] = pack2(((const float*)&sv[2])[j], ((const float*)&sv[3])[j]);
            w[2] = pack2(((const float*)&sv[4])[j], ((const float*)&sv[5])[j]);
            w[3] = pack2(((const float*)&sv[6])[j], ((const float*)&sv[7])[j]);
            *(u32x4*)&STb[(sc0 + j) * P_S + sb0] = w;   // 16B aligned
        }
    }
    // All G loads must be in registers before ANY out store (stage 3 of
    // trunk 0 overwrites this block's G slots). __syncthreads drains vmcnt(0)
    // per wave before s_barrier; the asm is belt-and-suspenders.
    asm volatile("s_waitcnt vmcnt(0)" ::: "memory");
    __syncthreads();

    #pragma unroll
    for (int tr = 0; tr < 2; ++tr) {
        const long tb = ((long)blockIdx.x * 2 + tr) * (TRUNK * DD);

        // ---- prefetch Q fragments (consumed in stage 3) --------------------
        F8 a3[2][2];   // [kt][mi]
        #pragma unroll
        for (int kt = 0; kt < 2; ++kt)
            #pragma unroll
            for (int mi = 0; mi < 2; ++mi) {
                const int r = (wave * 2 + mi) * 16 + l15;
                const float* qp = Q + tb + r * 64 + kt * 32 + quad * 8;
                float4 q0 = *(const float4*)qp;
                float4 q1 = *(const float4*)(qp + 4);
                a3[kt][mi].q[0] = pack2(q0.x, q0.y);
                a3[kt][mi].q[1] = pack2(q0.z, q0.w);
                a3[kt][mi].q[2] = pack2(q1.x, q1.y);
                a3[kt][mi].q[3] = pack2(q1.z, q1.w);
            }

        // ---- stage 2: H = G @ S  (A = G rows from regs, B = ST rows) -------
        f32x4 hacc[2][2] = {};
        #pragma unroll
        for (int kt = 0; kt < 2; ++kt) {
            const int kb = kt * 32 + quad * 8;
            F8 b2[2];
            #pragma unroll
            for (int ni = 0; ni < 2; ++ni)
                b2[ni].q = *(const u32x4*)&STb[((nt0 + ni) * 16 + l15) * P_S + kb];
            #pragma unroll
            for (int mi = 0; mi < 2; ++mi)
                #pragma unroll
                for (int ni = 0; ni < 2; ++ni)
                    hacc[mi][ni] = __builtin_amdgcn_mfma_f32_16x16x32_bf16(
                        gf[tr][kt][mi].v, b2[ni].v, hacc[mi][ni], 0, 0, 0);
        }
        // write HT[c][a]
        #pragma unroll
        for (int mi = 0; mi < 2; ++mi)
            #pragma unroll
            for (int ni = 0; ni < 2; ++ni) {
                const int hc  = (nt0 + ni) * 16 + l15;
                const int ha0 = (mt0 + mi) * 16 + quad * 4;
                const float* h = (const float*)&hacc[mi][ni];
                u32x2 w; w[0] = pack2(h[0], h[1]); w[1] = pack2(h[2], h[3]);
                *(u32x2*)&HTb[hc * P_S + ha0] = w;
            }
        __syncthreads();

        // ---- stage 3: out = Q @ H  (A = prefetched Q, B = HT rows) ---------
        f32x4 oacc[2][4] = {};
        #pragma unroll
        for (int kt = 0; kt < 2; ++kt) {
            const int ka = kt * 32 + quad * 8;
            #pragma unroll
            for (int ni = 0; ni < 4; ++ni) {
                F8 bb;
                bb.q = *(const u32x4*)&HTb[(ni * 16 + l15) * P_S + ka];
                #pragma unroll
                for (int mi = 0; mi < 2; ++mi)
                    oacc[mi][ni] = __builtin_amdgcn_mfma_f32_16x16x32_bf16(
                        a3[kt][mi].v, bb.v, oacc[mi][ni], 0, 0, 0);
            }
        }
        #pragma unroll
        for (int mi = 0; mi < 2; ++mi)
            #pragma unroll
            for (int ni = 0; ni < 4; ++ni) {
                const int row0 = (wave * 2 + mi) * 16 + quad * 4;
                const int col  = ni * 16 + l15;
                const float* o = (const float*)&oacc[mi][ni];
                #pragma unroll
                for (int reg = 0; reg < 4; ++reg)
                    out[tb + (long)(row0 + reg) * 64 + col] = o[reg];
            }
        if (tr == 0) __syncthreads();   // HTb reads done before next HT write
    }
}

extern "C" void kernel_launch(void* const* d_in, const int* in_sizes, int n_in,
                              void* d_out, int out_size, void* d_ws, size_t ws_size,
                              hipStream_t stream) {
    const float* Q = (const float*)d_in[0];
    const float* K = (const float*)d_in[1];
    const float* V = (const float*)d_in[2];
    float* out = (float*)d_out;
    float* S   = (float*)d_ws;                     // 4096 fp32 = 16 KB only

    const int n = in_sizes[0] / DD;                // 262144 rows
    const int T = n / TRUNK;                       // 2048 trunks

    u16* G = (u16*)out;                            // G pairs at region heads

    hipMemsetAsync(S, 0, DD * DD * sizeof(float), stream);
    g_kernel<<<T / 2, 256, 0, stream>>>(K, V, out);
    s_reduce<<<256, 256, 0, stream>>>(out, S);
    out_kernel<<<T / 2, 256, 0, stream>>>(Q, S, G, out);
}

// Round 7
// 236.037 us; speedup vs baseline: 1.0863x; 1.0863x over previous
//
#include <hip/hip_runtime.h>
#include <hip/hip_bf16.h>

// LinearAttentionTriton: out_t = Q_t @ (K_t^T @ V_t) @ S,  S = V^T K (fp32)
// N = 262144, D = 64, TRUNK = 128, fp32 in/out.
//
// Round-10: the scalar-gather g_kernel regressed (75 us, 4B loads ~2x slower
// per G13; per-block fixed costs dominate: 512x4=54.9 < 1024x2=58.9 <
// 2048x1=68.5). gs_kernel returns to the best-measured shape (512 blocks x
// 4 trunks, float4 staging) and adds:
//   - conflict-free ds_write_b128 staging (round-1 fix, conflicts 8x down)
//   - T14 cross-chunk prefetch: chunk c+1's 16 float4 loads issue before
//     chunk c's MFMA; pack+ds_write after the tail barrier -> HBM latency
//     of chunks 1-3 hides under compute.
//   - per-trunk G_t (bf16) emission so out_kernel never re-reads K,V.
//
// d_out memory map during the pipeline (region g = 64 KB for trunks
// {2g,2g+1}):
//   [g*64K      , g*64K+16K)  G pair (bf16)   g=0..1023  (gs_kernel -> out_kernel blk g)
//   [b*64K+16K  , b*64K+32K)  S-partial of gs block b, b=0..511 (-> s_reduce)
// out_kernel block g overwrites its whole region last; stream-serialized,
// regions disjoint. ws: 16 KB (S only).
// Numerics: identical MFMAs and f2bf rounding points as all passed rounds.

#define TRUNK 128
#define DD 64

typedef __bf16 bf16x8 __attribute__((ext_vector_type(8)));
typedef float  f32x4  __attribute__((ext_vector_type(4)));
typedef unsigned int   u32;
typedef unsigned short u16;
typedef u32 u32x4 __attribute__((ext_vector_type(4)));
typedef u32 u32x2 __attribute__((ext_vector_type(2)));

union F8 { bf16x8 v; u16 u[8]; u32x4 q; };

__device__ __forceinline__ u16 f2bf(float x) {
    union { float f; u32 u; } a; a.f = x;
    u32 u = a.u;
    return (u16)((u + 0x7FFFu + ((u >> 16) & 1u)) >> 16);
}
__device__ __forceinline__ u32 pack2(float a, float b) {
    return (u32)f2bf(a) | ((u32)f2bf(b) << 16);
}

#define P_S  72    // stride for 64x64 mats (ST/HT): 144 B rows
#define KV_T 136   // stride for transposed K^T/V^T (64 cols x 128 rows): 272 B

// ---- staging split for prefetch: load 8 float4 / thread, write 4 b128 ------
// thread t owns cols c0..c0+3 (c0=(t>>4)*4), rows r0..r0+7 (r0=(t&15)*8).
// write granule group = (c + lane) & 7 -> all 8 bank-groups: conflict-free.
__device__ __forceinline__ void load_T(const float* __restrict__ M, long tb,
                                       int t, float4 rw[8]) {
    const int c0 = (t >> 4) * 4;
    const int r0 = (t & 15) * 8;
    #pragma unroll
    for (int i = 0; i < 8; ++i)
        rw[i] = *(const float4*)(M + tb + (long)(r0 + i) * 64 + c0);
}
__device__ __forceinline__ void write_T(u16* __restrict__ MT, int t,
                                        const float4 rw[8]) {
    const int c0 = (t >> 4) * 4;
    const int r0 = (t & 15) * 8;
    #pragma unroll
    for (int j = 0; j < 4; ++j) {
        u32x4 w;
        w[0] = pack2(((const float*)&rw[0])[j], ((const float*)&rw[1])[j]);
        w[1] = pack2(((const float*)&rw[2])[j], ((const float*)&rw[3])[j]);
        w[2] = pack2(((const float*)&rw[4])[j], ((const float*)&rw[5])[j]);
        w[3] = pack2(((const float*)&rw[6])[j], ((const float*)&rw[7])[j]);
        *(u32x4*)&MT[(c0 + j) * KV_T + r0] = w;   // 16B, granule-aligned
    }
}

// ---------------- Kernel 1: per-trunk G_t + S-partials ----------------------
// 512 blocks x 256 threads, 4 trunks each, double-use LDS with cross-chunk
// register prefetch. Per trunk: stage K^T,V^T -> 16 MFMA -> G_t bf16 write,
// sacc accumulate. Block partial written fp32 to its region's 2nd 16 KB.
__global__ __launch_bounds__(256, 2) void gs_kernel(const float* __restrict__ K,
                                                    const float* __restrict__ V,
                                                    float* __restrict__ outb) {
    __shared__ __align__(16) u16 lds[2 * 64 * KV_T];
    u16* KT = lds;                  // [64][136]
    u16* VT = lds + 64 * KV_T;      // [64][136]

    const int t    = threadIdx.x;
    const int lane = t & 63;
    const int wave = t >> 6;
    const int l15  = lane & 15;
    const int quad = lane >> 4;
    const int mt0  = (wave >> 1) << 1;
    const int nt0  = (wave & 1) << 1;

    u16* G = (u16*)outb;
    f32x4 sacc[2][2] = {};

    const long base = (long)blockIdx.x * 4 * (TRUNK * DD);

    float4 kreg[8], vreg[8];
    load_T(K, base, t, kreg);
    load_T(V, base, t, vreg);
    write_T(KT, t, kreg);
    write_T(VT, t, vreg);

    #pragma unroll
    for (int c = 0; c < 4; ++c) {
        __syncthreads();            // chunk c staging visible

        // T14: issue chunk c+1 global loads now; they complete under the
        // MFMA/LDS-read work below and land in LDS after the tail barrier.
        if (c < 3) {
            const long nb = base + (long)(c + 1) * (TRUNK * DD);
            load_T(K, nb, t, kreg);
            load_T(V, nb, t, vreg);
        }

        // C1[b][a] = sum_r V[r][b] K[r][a]  (A = V cols, B = K cols)
        f32x4 gacc[2][2] = {};
        #pragma unroll
        for (int kt = 0; kt < 4; ++kt) {
            const int rbase = kt * 32 + quad * 8;
            F8 af[2], bf[2];
            #pragma unroll
            for (int mi = 0; mi < 2; ++mi)
                af[mi].q = *(const u32x4*)&VT[((mt0 + mi) * 16 + l15) * KV_T + rbase];
            #pragma unroll
            for (int ni = 0; ni < 2; ++ni)
                bf[ni].q = *(const u32x4*)&KT[((nt0 + ni) * 16 + l15) * KV_T + rbase];
            #pragma unroll
            for (int mi = 0; mi < 2; ++mi)
                #pragma unroll
                for (int ni = 0; ni < 2; ++ni)
                    gacc[mi][ni] = __builtin_amdgcn_mfma_f32_16x16x32_bf16(
                        af[mi].v, bf[ni].v, gacc[mi][ni], 0, 0, 0);
        }

        // G_t[a][b] = C1[b][a], bf16, region-head slot; accumulate S-partial.
        const int tt = blockIdx.x * 4 + c;
        u16* Gt = G + ((size_t)(tt >> 1) * 32768 + (size_t)(tt & 1) * 4096);
        #pragma unroll
        for (int mi = 0; mi < 2; ++mi)
            #pragma unroll
            for (int ni = 0; ni < 2; ++ni) {
                const int ga  = (nt0 + ni) * 16 + l15;        // G row a
                const int gb0 = (mt0 + mi) * 16 + quad * 4;   // G col b0..b0+3
                const float* g = (const float*)&gacc[mi][ni];
                u32x2 w; w[0] = pack2(g[0], g[1]); w[1] = pack2(g[2], g[3]);
                *(u32x2*)&Gt[ga * 64 + gb0] = w;
                sacc[mi][ni] += gacc[mi][ni];
            }

        __syncthreads();            // LDS reads of chunk c done
        if (c < 3) {                // compiler waits vmcnt on kreg/vreg here
            write_T(KT, t, kreg);
            write_T(VT, t, vreg);
        }
    }

    // fp32 S-partial (natural layout) at [block*64K + 16K, +16K) of d_out
    float* o = outb + (size_t)blockIdx.x * 16384 + 4096;
    #pragma unroll
    for (int mi = 0; mi < 2; ++mi)
        #pragma unroll
        for (int ni = 0; ni < 2; ++ni) {
            const int b0 = (mt0 + mi) * 16 + quad * 4;
            const int a  = (nt0 + ni) * 16 + l15;
            const float* g = (const float*)&sacc[mi][ni];
            #pragma unroll
            for (int reg = 0; reg < 4; ++reg)
                o[(b0 + reg) * 64 + a] = g[reg];
        }
}

// ---------------- Kernel A2: reduce 512 partials -> S (fp32) ----------------
// 32768 threads = 1024 float4-groups x 32 ways; 32 atomics/address. S zeroed.
// Partial b lives at float4 offset b*4096 + 1024 of d_out.
__global__ __launch_bounds__(256) void s_reduce(const float* __restrict__ Pb,
                                                float* __restrict__ S) {
    const int tid = blockIdx.x * 256 + threadIdx.x;  // [0, 32768)
    const int eg  = tid & 1023;                       // float4 group of S
    const int way = tid >> 10;                        // [0, 32)
    const float4* p = (const float4*)Pb;
    float4 acc = {0.f, 0.f, 0.f, 0.f};
    #pragma unroll 4
    for (int i = 0; i < 16; ++i) {
        float4 v = p[(size_t)(way * 16 + i) * 4096 + 1024 + eg];
        acc.x += v.x; acc.y += v.y; acc.z += v.z; acc.w += v.w;
    }
    atomicAdd(&S[eg * 4 + 0], acc.x);
    atomicAdd(&S[eg * 4 + 1], acc.y);
    atomicAdd(&S[eg * 4 + 2], acc.z);
    atomicAdd(&S[eg * 4 + 3], acc.w);
}

// ---------------- Kernel 2: out_t = Q_t @ G_t @ S ---------------------------
// (verbatim from the passed round-2/6 kernel)
// 1024 blocks x 256 threads, 2 trunks each. Reads Q + G (bf16) + S (fp32,
// L2-resident). LDS = S^T + HT only (18432 B). One G-drain barrier, then
// 2 barriers per trunk.
#define LDS3 (2 * 64 * P_S)     // ST (4608 u16) + HT (4608 u16)

__global__ __launch_bounds__(256, 3) void out_kernel(const float* __restrict__ Q,
                                                     const float* __restrict__ S,
                                                     const u16* __restrict__ G,
                                                     float* __restrict__ out) {
    __shared__ __align__(16) u16 lds[LDS3];
    u16* STb = lds;                 // [64][72]  S^T bf16
    u16* HTb = lds + 64 * P_S;      // [64][72]  H^T bf16 (per trunk, reused)

    const int t    = threadIdx.x;
    const int lane = t & 63;
    const int wave = t >> 6;
    const int l15  = lane & 15;
    const int quad = lane >> 4;
    const int mt0  = (wave >> 1) << 1;
    const int nt0  = (wave & 1) << 1;

    // ---- issue G loads for both trunks (A-frags of stage 2) ----------------
    const u16* Gblk = G + (size_t)blockIdx.x * 32768;   // this block's 16 KB
    F8 gf[2][2][2];   // [trunk][kt][mi]
    #pragma unroll
    for (int tr = 0; tr < 2; ++tr)
        #pragma unroll
        for (int kt = 0; kt < 2; ++kt)
            #pragma unroll
            for (int mi = 0; mi < 2; ++mi)
                gf[tr][kt][mi].q = *(const u32x4*)&Gblk[(size_t)tr * 4096 +
                    ((mt0 + mi) * 16 + l15) * 64 + kt * 32 + quad * 8];

    // ---- stage S^T into LDS (fp32 S -> bf16, transposed) -------------------
    {
        const int sb0 = (t & 7) * 8;        // 0..56
        const int sc0 = (t >> 3) * 2;       // 0..62
        float2 sv[8];
        #pragma unroll
        for (int i = 0; i < 8; ++i)
            sv[i] = *(const float2*)(S + (sb0 + i) * 64 + sc0);
        #pragma unroll
        for (int j = 0; j < 2; ++j) {
            u32x4 w;
            w[0] = pack2(((const float*)&sv[0])[j], ((const float*)&sv[1])[j]);
            w[1] = pack2(((const float*)&sv[2])[j], ((const float*)&sv[3])[j]);
            w[2] = pack2(((const float*)&sv[4])[j], ((const float*)&sv[5])[j]);
            w[3] = pack2(((const float*)&sv[6])[j], ((const float*)&sv[7])[j]);
            *(u32x4*)&STb[(sc0 + j) * P_S + sb0] = w;   // 16B aligned
        }
    }
    // All G loads must be in registers before ANY out store (stage 3 of
    // trunk 0 overwrites this block's G slots). __syncthreads drains vmcnt(0)
    // per wave before s_barrier; the asm is belt-and-suspenders.
    asm volatile("s_waitcnt vmcnt(0)" ::: "memory");
    __syncthreads();

    #pragma unroll
    for (int tr = 0; tr < 2; ++tr) {
        const long tb = ((long)blockIdx.x * 2 + tr) * (TRUNK * DD);

        // ---- prefetch Q fragments (consumed in stage 3) --------------------
        F8 a3[2][2];   // [kt][mi]
        #pragma unroll
        for (int kt = 0; kt < 2; ++kt)
            #pragma unroll
            for (int mi = 0; mi < 2; ++mi) {
                const int r = (wave * 2 + mi) * 16 + l15;
                const float* qp = Q + tb + r * 64 + kt * 32 + quad * 8;
                float4 q0 = *(const float4*)qp;
                float4 q1 = *(const float4*)(qp + 4);
                a3[kt][mi].q[0] = pack2(q0.x, q0.y);
                a3[kt][mi].q[1] = pack2(q0.z, q0.w);
                a3[kt][mi].q[2] = pack2(q1.x, q1.y);
                a3[kt][mi].q[3] = pack2(q1.z, q1.w);
            }

        // ---- stage 2: H = G @ S  (A = G rows from regs, B = ST rows) -------
        f32x4 hacc[2][2] = {};
        #pragma unroll
        for (int kt = 0; kt < 2; ++kt) {
            const int kb = kt * 32 + quad * 8;
            F8 b2[2];
            #pragma unroll
            for (int ni = 0; ni < 2; ++ni)
                b2[ni].q = *(const u32x4*)&STb[((nt0 + ni) * 16 + l15) * P_S + kb];
            #pragma unroll
            for (int mi = 0; mi < 2; ++mi)
                #pragma unroll
                for (int ni = 0; ni < 2; ++ni)
                    hacc[mi][ni] = __builtin_amdgcn_mfma_f32_16x16x32_bf16(
                        gf[tr][kt][mi].v, b2[ni].v, hacc[mi][ni], 0, 0, 0);
        }
        // write HT[c][a]
        #pragma unroll
        for (int mi = 0; mi < 2; ++mi)
            #pragma unroll
            for (int ni = 0; ni < 2; ++ni) {
                const int hc  = (nt0 + ni) * 16 + l15;
                const int ha0 = (mt0 + mi) * 16 + quad * 4;
                const float* h = (const float*)&hacc[mi][ni];
                u32x2 w; w[0] = pack2(h[0], h[1]); w[1] = pack2(h[2], h[3]);
                *(u32x2*)&HTb[hc * P_S + ha0] = w;
            }
        __syncthreads();

        // ---- stage 3: out = Q @ H  (A = prefetched Q, B = HT rows) ---------
        f32x4 oacc[2][4] = {};
        #pragma unroll
        for (int kt = 0; kt < 2; ++kt) {
            const int ka = kt * 32 + quad * 8;
            #pragma unroll
            for (int ni = 0; ni < 4; ++ni) {
                F8 bb;
                bb.q = *(const u32x4*)&HTb[(ni * 16 + l15) * P_S + ka];
                #pragma unroll
                for (int mi = 0; mi < 2; ++mi)
                    oacc[mi][ni] = __builtin_amdgcn_mfma_f32_16x16x32_bf16(
                        a3[kt][mi].v, bb.v, oacc[mi][ni], 0, 0, 0);
            }
        }
        #pragma unroll
        for (int mi = 0; mi < 2; ++mi)
            #pragma unroll
            for (int ni = 0; ni < 4; ++ni) {
                const int row0 = (wave * 2 + mi) * 16 + quad * 4;
                const int col  = ni * 16 + l15;
                const float* o = (const float*)&oacc[mi][ni];
                #pragma unroll
                for (int reg = 0; reg < 4; ++reg)
                    out[tb + (long)(row0 + reg) * 64 + col] = o[reg];
            }
        if (tr == 0) __syncthreads();   // HTb reads done before next HT write
    }
}

extern "C" void kernel_launch(void* const* d_in, const int* in_sizes, int n_in,
                              void* d_out, int out_size, void* d_ws, size_t ws_size,
                              hipStream_t stream) {
    const float* Q = (const float*)d_in[0];
    const float* K = (const float*)d_in[1];
    const float* V = (const float*)d_in[2];
    float* out = (float*)d_out;
    float* S   = (float*)d_ws;                     // 4096 fp32 = 16 KB only

    const int n = in_sizes[0] / DD;                // 262144 rows
    const int T = n / TRUNK;                       // 2048 trunks

    u16* G = (u16*)out;                            // G pairs at region heads

    hipMemsetAsync(S, 0, DD * DD * sizeof(float), stream);
    gs_kernel<<<T / 4, 256, 0, stream>>>(K, V, out);
    s_reduce<<<128, 256, 0, stream>>>(out, S);
    out_kernel<<<T / 2, 256, 0, stream>>>(Q, S, G, out);
}